// Round 1
// baseline (6185.687 us; speedup 1.0000x reference)
//
#include <hip/hip_runtime.h>

// ---------------- softmax of the two 3-element attention vectors ----------
__global__ void prep_softmax(const float* __restrict__ a1,
                             const float* __restrict__ a2,
                             float* __restrict__ sa, int D)
{
    if (blockIdx.x == 0 && threadIdx.x == 0) {
        float m1 = -1e30f, m2 = -1e30f;
        for (int i = 0; i < D; ++i) { m1 = fmaxf(m1, a1[i]); m2 = fmaxf(m2, a2[i]); }
        float s1 = 0.f, s2 = 0.f;
        for (int i = 0; i < D; ++i) { s1 += expf(a1[i] - m1); s2 += expf(a2[i] - m2); }
        for (int i = 0; i < D; ++i) {
            sa[i]     = expf(a1[i] - m1) / s1;
            sa[8 + i] = expf(a2[i] - m2) / s2;
        }
    }
}

// ---------------- fp32 tiled GEMM: out[M,N] = act(A)[M,K] @ W[K,N] + bias --
// BM=64, BN=64, BK=16, 256 threads, 4x4 register block per thread.
template <bool LEAKY_IN>
__global__ __launch_bounds__(256)
void gemm_bias(const float* __restrict__ A,   // [M,K]
               const float* __restrict__ W,   // [K,N]
               const float* __restrict__ bias,// [N]
               float* __restrict__ out,       // [M,N]
               int M, int K, int N)
{
    const int BM = 64, BN = 64, BK = 16;
    __shared__ float As[BK][BM + 4];  // +4 pad: 16B-aligned float4 rows, spread banks
    __shared__ float Ws[BK][BN];

    const int m0 = blockIdx.x * BM;
    const int n0 = blockIdx.y * BN;
    const int tid = threadIdx.x;
    const int tr = tid >> 4;   // 0..15 -> rows tr*4..tr*4+3
    const int tc = tid & 15;   // 0..15 -> cols tc*4..tc*4+3

    float acc[4][4] = {};

    const int nk = (K + BK - 1) / BK;
    for (int t = 0; t < nk; ++t) {
        const int k0 = t * BK;
        // A tile: 64x16 (m-major, k fastest) -> store transposed As[k][m]
        #pragma unroll
        for (int i = 0; i < 4; ++i) {
            int idx = tid + i * 256;
            int m = idx >> 4;
            int k = idx & 15;
            int gm = m0 + m, gk = k0 + k;
            float v = 0.f;
            if (gm < M && gk < K) {
                v = A[(long)gm * K + gk];
                if (LEAKY_IN) v = (v >= 0.f) ? v : 0.2f * v;
            }
            As[k][m] = v;
        }
        // W tile: 16x64
        #pragma unroll
        for (int i = 0; i < 4; ++i) {
            int idx = tid + i * 256;
            int k = idx >> 6;
            int n = idx & 63;
            int gk = k0 + k;
            Ws[k][n] = (gk < K) ? W[(long)gk * N + n0 + n] : 0.f;
        }
        __syncthreads();

        #pragma unroll
        for (int kk = 0; kk < BK; ++kk) {
            float4 av = *reinterpret_cast<const float4*>(&As[kk][tr * 4]);
            float4 wv = *reinterpret_cast<const float4*>(&Ws[kk][tc * 4]);
            float a[4] = {av.x, av.y, av.z, av.w};
            float w[4] = {wv.x, wv.y, wv.z, wv.w};
            #pragma unroll
            for (int r = 0; r < 4; ++r)
                #pragma unroll
                for (int c = 0; c < 4; ++c)
                    acc[r][c] += a[r] * w[c];
        }
        __syncthreads();
    }

    // store (+bias), float4 per row
    #pragma unroll
    for (int r = 0; r < 4; ++r) {
        int gm = m0 + tr * 4 + r;
        if (gm < M) {
            int gn = n0 + tc * 4;
            float4 o;
            o.x = acc[r][0] + bias[gn + 0];
            o.y = acc[r][1] + bias[gn + 1];
            o.z = acc[r][2] + bias[gn + 2];
            o.w = acc[r][3] + bias[gn + 3];
            *reinterpret_cast<float4*>(&out[(long)gm * N + gn]) = o;
        }
    }
}

// ---------------- edge aggregation: out[row] += sa[d]*edge_w[e] * support[col]
// C == 128: 32 threads per edge, one float4 of channels per thread.
__global__ __launch_bounds__(256)
void aggregate(const float* __restrict__ support, // [N, C]
               const float* __restrict__ edge_w,  // [D*E]
               const int* __restrict__ rows,      // [D*E]
               const int* __restrict__ cols,      // [D*E]
               const float* __restrict__ sa,      // softmax weights, sa[d]
               float* __restrict__ out,           // [N, C] (accumulated)
               int E, int D, int C)
{
    long gid = (long)blockIdx.x * blockDim.x + threadIdx.x;
    long total = (long)D * E * (C >> 2);
    if (gid >= total) return;

    int sub = (int)(gid & 31);   // C/4 == 32 channel groups
    int e   = (int)(gid >> 5);   // global edge id in [0, D*E)
    int d   = e / E;

    float coeff = sa[d] * edge_w[e];
    int r = rows[e];
    int c = cols[e];

    const float4 v = *reinterpret_cast<const float4*>(&support[(long)c * C + sub * 4]);
    float* dst = &out[(long)r * C + sub * 4];
    atomicAdd(dst + 0, coeff * v.x);
    atomicAdd(dst + 1, coeff * v.y);
    atomicAdd(dst + 2, coeff * v.z);
    atomicAdd(dst + 3, coeff * v.w);
}

// ---------------- L2 row normalize in place (one wave per row) -------------
__global__ __launch_bounds__(256)
void l2norm_rows(float* __restrict__ h, int M, int C)
{
    int wid  = (int)((blockIdx.x * (long)blockDim.x + threadIdx.x) >> 6);
    int lane = threadIdx.x & 63;
    if (wid >= M) return;
    float* p = h + (long)wid * C;
    float s = 0.f;
    for (int j = lane; j < C; j += 64) { float v = p[j]; s += v * v; }
    #pragma unroll
    for (int off = 32; off; off >>= 1) s += __shfl_xor(s, off);
    float inv = 1.f / fmaxf(sqrtf(s), 1e-12f);
    for (int j = lane; j < C; j += 64) p[j] *= inv;
}

extern "C" void kernel_launch(void* const* d_in, const int* in_sizes, int n_in,
                              void* d_out, int out_size, void* d_ws, size_t ws_size,
                              hipStream_t stream)
{
    const float* x      = (const float*)d_in[0];
    const float* edge_w = (const float*)d_in[1];
    const float* w1     = (const float*)d_in[2];
    const float* b1     = (const float*)d_in[3];
    const float* a1     = (const float*)d_in[4];
    const float* w2     = (const float*)d_in[5];
    const float* b2     = (const float*)d_in[6];
    const float* a2     = (const float*)d_in[7];
    const int*   rows   = (const int*)d_in[8];
    const int*   cols   = (const int*)d_in[9];

    const int D    = in_sizes[4];            // 3
    const int HID  = in_sizes[3];            // 128
    const int OUTC = in_sizes[6];            // 128
    const int INC  = in_sizes[2] / HID;      // 300
    const int N    = in_sizes[0] / INC;      // 50000
    const int E    = in_sizes[1] / D;        // 600000

    float* out = (float*)d_out;

    char* ws = (char*)d_ws;
    size_t suppBytes = (size_t)N * HID * sizeof(float);
    float* supp   = (float*)ws;                    // [N, HID] support buffer
    float* aggbuf = (float*)(ws + suppBytes);      // [N, HID] layer-1 aggregate
    float* sa     = (float*)(ws + 2 * suppBytes);  // 16 floats softmax scratch

    // zero accumulators (d_out/ws are poisoned, not re-zeroed by harness)
    hipMemsetAsync(aggbuf, 0, suppBytes, stream);
    hipMemsetAsync(d_out, 0, (size_t)out_size * sizeof(float), stream);

    prep_softmax<<<1, 64, 0, stream>>>(a1, a2, sa, D);

    // layer 1: supp = x @ w1 + b1
    dim3 g1((N + 63) / 64, HID / 64);
    gemm_bias<false><<<g1, 256, 0, stream>>>(x, w1, b1, supp, N, INC, HID);

    // layer 1 aggregation into aggbuf
    long tot = (long)D * E * (HID / 4);
    int ablocks = (int)((tot + 255) / 256);
    aggregate<<<ablocks, 256, 0, stream>>>(supp, edge_w, rows, cols, sa, aggbuf, E, D, HID);

    // layer 2: supp = leaky(aggbuf) @ w2 + b2
    dim3 g2((N + 63) / 64, OUTC / 64);
    gemm_bias<true><<<g2, 256, 0, stream>>>(aggbuf, w2, b2, supp, N, HID, OUTC);

    // layer 2 aggregation directly into d_out
    aggregate<<<ablocks, 256, 0, stream>>>(supp, edge_w, rows, cols, sa + 8, out, E, D, OUTC);

    // final L2 row normalization in place
    int nblocks = (N + 3) / 4;  // 4 waves (rows) per 256-thread block
    l2norm_rows<<<nblocks, 256, 0, stream>>>(out, N, OUTC);
}

// Round 2
// 772.268 us; speedup vs baseline: 8.0098x; 8.0098x over previous
//
#include <hip/hip_runtime.h>

#define SCAN_T 256
#define SCAN_E 8
#define SCAN_CHUNK (SCAN_T * SCAN_E)   // 2048

// ---------------- softmax of the two 3-element attention vectors ----------
__global__ void prep_softmax(const float* __restrict__ a1,
                             const float* __restrict__ a2,
                             float* __restrict__ sa, int D)
{
    if (blockIdx.x == 0 && threadIdx.x == 0) {
        float m1 = -1e30f, m2 = -1e30f;
        for (int i = 0; i < D; ++i) { m1 = fmaxf(m1, a1[i]); m2 = fmaxf(m2, a2[i]); }
        float s1 = 0.f, s2 = 0.f;
        for (int i = 0; i < D; ++i) { s1 += expf(a1[i] - m1); s2 += expf(a2[i] - m2); }
        for (int i = 0; i < D; ++i) {
            sa[i]     = expf(a1[i] - m1) / s1;
            sa[8 + i] = expf(a2[i] - m2) / s2;
        }
    }
}

// ---------------- CSR build ------------------------------------------------
__global__ __launch_bounds__(256)
void count_edges(const int* __restrict__ rows, int* __restrict__ counts,
                 int E, int D, int N)
{
    int e = blockIdx.x * blockDim.x + threadIdx.x;
    if (e >= D * E) return;
    int d = e / E;
    atomicAdd(&counts[d * N + rows[e]], 1);
}

__global__ __launch_bounds__(SCAN_T)
void scan_partials(const int* __restrict__ cnt, int* __restrict__ psum, int n)
{
    __shared__ int sdata[SCAN_T];
    int t = threadIdx.x;
    int base = blockIdx.x * SCAN_CHUNK + t * SCAN_E;
    int s = 0;
    #pragma unroll
    for (int i = 0; i < SCAN_E; ++i) { int idx = base + i; if (idx < n) s += cnt[idx]; }
    sdata[t] = s; __syncthreads();
    for (int off = SCAN_T / 2; off; off >>= 1) {
        if (t < off) sdata[t] += sdata[t + off];
        __syncthreads();
    }
    if (t == 0) psum[blockIdx.x] = sdata[0];
}

__global__ void scan_psum(int* __restrict__ psum, int nchunks)
{
    if (blockIdx.x == 0 && threadIdx.x == 0) {
        int run = 0;
        for (int i = 0; i < nchunks; ++i) { int v = psum[i]; psum[i] = run; run += v; }
    }
}

__global__ __launch_bounds__(SCAN_T)
void scan_scatter(const int* __restrict__ cnt, const int* __restrict__ psum,
                  int* __restrict__ off, int* __restrict__ cursor, int n)
{
    __shared__ int lsum[SCAN_T];
    int t = threadIdx.x;
    int base = blockIdx.x * SCAN_CHUNK + t * SCAN_E;
    int loc[SCAN_E];
    int s = 0;
    #pragma unroll
    for (int i = 0; i < SCAN_E; ++i) {
        int idx = base + i;
        int v = (idx < n) ? cnt[idx] : 0;
        loc[i] = s; s += v;
    }
    lsum[t] = s; __syncthreads();
    // inclusive Hillis-Steele scan of per-thread sums
    for (int o = 1; o < SCAN_T; o <<= 1) {
        int v = (t >= o) ? lsum[t - o] : 0;
        __syncthreads();
        if (t >= o) lsum[t] += v;
        __syncthreads();
    }
    int texcl = lsum[t] - s;   // exclusive prefix for this thread
    int cbase = psum[blockIdx.x];
    #pragma unroll
    for (int i = 0; i < SCAN_E; ++i) {
        int idx = base + i;
        if (idx < n) {
            int o = cbase + texcl + loc[i];
            off[idx] = o;
            cursor[idx] = o;
        }
    }
}

__global__ __launch_bounds__(256)
void csr_fill(const int* __restrict__ rows, const int* __restrict__ cols,
              const float* __restrict__ ew_in, int* __restrict__ cursor,
              int* __restrict__ ecol, float* __restrict__ ew_out,
              int E, int D, int N)
{
    int e = blockIdx.x * blockDim.x + threadIdx.x;
    if (e >= D * E) return;
    int d = e / E;
    int pos = atomicAdd(&cursor[d * N + rows[e]], 1);
    ecol[pos] = cols[e];
    ew_out[pos] = ew_in[e];
}

// ---------------- fp32 tiled GEMM: out[M,N] = act(A)[M,K] @ W[K,N] + bias --
template <bool LEAKY_IN>
__global__ __launch_bounds__(256)
void gemm_bias(const float* __restrict__ A,   // [M,K]
               const float* __restrict__ W,   // [K,N]
               const float* __restrict__ bias,// [N]
               float* __restrict__ out,       // [M,N]
               int M, int K, int N)
{
    const int BM = 64, BN = 64, BK = 16;
    __shared__ float As[BK][BM + 4];
    __shared__ float Ws[BK][BN];

    const int m0 = blockIdx.x * BM;
    const int n0 = blockIdx.y * BN;
    const int tid = threadIdx.x;
    const int tr = tid >> 4;
    const int tc = tid & 15;

    float acc[4][4] = {};

    const int nk = (K + BK - 1) / BK;
    for (int t = 0; t < nk; ++t) {
        const int k0 = t * BK;
        #pragma unroll
        for (int i = 0; i < 4; ++i) {
            int idx = tid + i * 256;
            int m = idx >> 4;
            int k = idx & 15;
            int gm = m0 + m, gk = k0 + k;
            float v = 0.f;
            if (gm < M && gk < K) {
                v = A[(long)gm * K + gk];
                if (LEAKY_IN) v = (v >= 0.f) ? v : 0.2f * v;
            }
            As[k][m] = v;
        }
        #pragma unroll
        for (int i = 0; i < 4; ++i) {
            int idx = tid + i * 256;
            int k = idx >> 6;
            int n = idx & 63;
            int gk = k0 + k;
            Ws[k][n] = (gk < K) ? W[(long)gk * N + n0 + n] : 0.f;
        }
        __syncthreads();

        #pragma unroll
        for (int kk = 0; kk < BK; ++kk) {
            float4 av = *reinterpret_cast<const float4*>(&As[kk][tr * 4]);
            float4 wv = *reinterpret_cast<const float4*>(&Ws[kk][tc * 4]);
            float a[4] = {av.x, av.y, av.z, av.w};
            float w[4] = {wv.x, wv.y, wv.z, wv.w};
            #pragma unroll
            for (int r = 0; r < 4; ++r)
                #pragma unroll
                for (int c = 0; c < 4; ++c)
                    acc[r][c] += a[r] * w[c];
        }
        __syncthreads();
    }

    #pragma unroll
    for (int r = 0; r < 4; ++r) {
        int gm = m0 + tr * 4 + r;
        if (gm < M) {
            int gn = n0 + tc * 4;
            float4 o;
            o.x = acc[r][0] + bias[gn + 0];
            o.y = acc[r][1] + bias[gn + 1];
            o.z = acc[r][2] + bias[gn + 2];
            o.w = acc[r][3] + bias[gn + 3];
            *reinterpret_cast<float4*>(&out[(long)gm * N + gn]) = o;
        }
    }
}

// ---------------- CSR aggregation: one wave per output row -----------------
// C == 128: each of the 64 lanes owns a float2 of channels. No atomics.
__global__ __launch_bounds__(256)
void aggregate_csr(const float* __restrict__ supp,  // [N,128]
                   const int* __restrict__ off,     // [D*N]
                   const int* __restrict__ cnt,     // [D*N]
                   const int* __restrict__ ecol,    // [D*E]
                   const float* __restrict__ ew,    // [D*E]
                   const float* __restrict__ sa,    // [D]
                   float* __restrict__ out,         // [N,128]
                   int N, int D)
{
    int row = blockIdx.x * 4 + (threadIdx.x >> 6);
    int lane = threadIdx.x & 63;
    if (row >= N) return;

    float accx = 0.f, accy = 0.f;
    for (int d = 0; d < D; ++d) {
        float coeff = sa[d];
        int seg = d * N + row;
        int base = off[seg];
        int c = cnt[seg];
        for (int j = 0; j < c; ++j) {
            int col = ecol[base + j];
            float w = ew[base + j] * coeff;
            const float2 v = *reinterpret_cast<const float2*>(
                &supp[(long)col * 128 + lane * 2]);
            accx += w * v.x;
            accy += w * v.y;
        }
    }
    float2 o; o.x = accx; o.y = accy;
    *reinterpret_cast<float2*>(&out[(long)row * 128 + lane * 2]) = o;
}

// ---------------- L2 row normalize in place (one wave per row) -------------
__global__ __launch_bounds__(256)
void l2norm_rows(float* __restrict__ h, int M, int C)
{
    int wid  = (int)((blockIdx.x * (long)blockDim.x + threadIdx.x) >> 6);
    int lane = threadIdx.x & 63;
    if (wid >= M) return;
    float* p = h + (long)wid * C;
    float s = 0.f;
    for (int j = lane; j < C; j += 64) { float v = p[j]; s += v * v; }
    #pragma unroll
    for (int off = 32; off; off >>= 1) s += __shfl_xor(s, off);
    float inv = 1.f / fmaxf(sqrtf(s), 1e-12f);
    for (int j = lane; j < C; j += 64) p[j] *= inv;
}

extern "C" void kernel_launch(void* const* d_in, const int* in_sizes, int n_in,
                              void* d_out, int out_size, void* d_ws, size_t ws_size,
                              hipStream_t stream)
{
    const float* x      = (const float*)d_in[0];
    const float* edge_w = (const float*)d_in[1];
    const float* w1     = (const float*)d_in[2];
    const float* b1     = (const float*)d_in[3];
    const float* a1     = (const float*)d_in[4];
    const float* w2     = (const float*)d_in[5];
    const float* b2     = (const float*)d_in[6];
    const float* a2     = (const float*)d_in[7];
    const int*   rows   = (const int*)d_in[8];
    const int*   cols   = (const int*)d_in[9];

    const int D    = in_sizes[4];            // 3
    const int HID  = in_sizes[3];            // 128
    const int OUTC = in_sizes[6];            // 128
    const int INC  = in_sizes[2] / HID;      // 300
    const int N    = in_sizes[0] / INC;      // 50000
    const int E    = in_sizes[1] / D;        // 600000

    const int DN = D * N;
    const long DE = (long)D * E;

    float* out = (float*)d_out;

    // ---- workspace layout (all 256B-aligned) ----
    char* ws = (char*)d_ws;
    size_t p = 0;
    auto alloc = [&](size_t bytes) { void* q = ws + p; p = (p + bytes + 255) & ~(size_t)255; return q; };
    float* supp   = (float*)alloc((size_t)N * HID * sizeof(float));  // 25.6 MB
    int*   counts = (int*)alloc((size_t)DN * sizeof(int));
    int*   off    = (int*)alloc((size_t)DN * sizeof(int));
    int*   cursor = (int*)alloc((size_t)DN * sizeof(int));
    int*   psum   = (int*)alloc(1024 * sizeof(int));
    int*   ecol   = (int*)alloc((size_t)DE * sizeof(int));           // 7.2 MB
    float* ew     = (float*)alloc((size_t)DE * sizeof(float));       // 7.2 MB
    float* sa     = (float*)alloc(64 * sizeof(float));

    // ---- CSR build ----
    hipMemsetAsync(counts, 0, (size_t)DN * sizeof(int), stream);
    prep_softmax<<<1, 64, 0, stream>>>(a1, a2, sa, D);

    int eblocks = (int)((DE + 255) / 256);
    count_edges<<<eblocks, 256, 0, stream>>>(rows, counts, E, D, N);

    int nchunks = (DN + SCAN_CHUNK - 1) / SCAN_CHUNK;
    scan_partials<<<nchunks, SCAN_T, 0, stream>>>(counts, psum, DN);
    scan_psum<<<1, 64, 0, stream>>>(psum, nchunks);
    scan_scatter<<<nchunks, SCAN_T, 0, stream>>>(counts, psum, off, cursor, DN);

    csr_fill<<<eblocks, 256, 0, stream>>>(rows, cols, edge_w, cursor, ecol, ew, E, D, N);

    // ---- layer 1 ----
    dim3 g1((N + 63) / 64, HID / 64);
    gemm_bias<false><<<g1, 256, 0, stream>>>(x, w1, b1, supp, N, INC, HID);

    int rblocks = (N + 3) / 4;
    aggregate_csr<<<rblocks, 256, 0, stream>>>(supp, off, counts, ecol, ew, sa, out, N, D);

    // ---- layer 2 (leaky applied while reading layer-1 output) ----
    dim3 g2((N + 63) / 64, OUTC / 64);
    gemm_bias<true><<<g2, 256, 0, stream>>>(out, w2, b2, supp, N, HID, OUTC);

    aggregate_csr<<<rblocks, 256, 0, stream>>>(supp, off, counts, ecol, ew, sa + 8, out, N, D);

    // ---- final L2 row normalization ----
    int nblocks = (N + 3) / 4;
    l2norm_rows<<<nblocks, 256, 0, stream>>>(out, N, OUTC);
}

// Round 3
// 479.166 us; speedup vs baseline: 12.9093x; 1.6117x over previous
//
#include <hip/hip_runtime.h>
#include <hip/hip_fp16.h>

#define SCAN_T 256
#define SCAN_E 8
#define SCAN_CHUNK (SCAN_T * SCAN_E)   // 2048

// ---------------- softmax of the two 3-element attention vectors ----------
__global__ void prep_softmax(const float* __restrict__ a1,
                             const float* __restrict__ a2,
                             float* __restrict__ sa, int D)
{
    if (blockIdx.x == 0 && threadIdx.x == 0) {
        float m1 = -1e30f, m2 = -1e30f;
        for (int i = 0; i < D; ++i) { m1 = fmaxf(m1, a1[i]); m2 = fmaxf(m2, a2[i]); }
        float s1 = 0.f, s2 = 0.f;
        for (int i = 0; i < D; ++i) { s1 += expf(a1[i] - m1); s2 += expf(a2[i] - m2); }
        for (int i = 0; i < D; ++i) {
            sa[i]     = expf(a1[i] - m1) / s1;
            sa[8 + i] = expf(a2[i] - m2) / s2;
        }
    }
}

// ---------------- CSR build (one segment per row, all relations merged) ----
__global__ __launch_bounds__(256)
void count_edges(const int* __restrict__ rows, int* __restrict__ counts,
                 int DE)
{
    int e = blockIdx.x * blockDim.x + threadIdx.x;
    if (e >= DE) return;
    atomicAdd(&counts[rows[e]], 1);
}

__global__ __launch_bounds__(SCAN_T)
void scan_partials(const int* __restrict__ cnt, int* __restrict__ psum, int n)
{
    __shared__ int sdata[SCAN_T];
    int t = threadIdx.x;
    int base = blockIdx.x * SCAN_CHUNK + t * SCAN_E;
    int s = 0;
    #pragma unroll
    for (int i = 0; i < SCAN_E; ++i) { int idx = base + i; if (idx < n) s += cnt[idx]; }
    sdata[t] = s; __syncthreads();
    for (int off = SCAN_T / 2; off; off >>= 1) {
        if (t < off) sdata[t] += sdata[t + off];
        __syncthreads();
    }
    if (t == 0) psum[blockIdx.x] = sdata[0];
}

__global__ void scan_psum(int* __restrict__ psum, int nchunks)
{
    if (blockIdx.x == 0 && threadIdx.x == 0) {
        int run = 0;
        for (int i = 0; i < nchunks; ++i) { int v = psum[i]; psum[i] = run; run += v; }
    }
}

__global__ __launch_bounds__(SCAN_T)
void scan_scatter(const int* __restrict__ cnt, const int* __restrict__ psum,
                  int* __restrict__ off, int* __restrict__ cursor, int n)
{
    __shared__ int lsum[SCAN_T];
    int t = threadIdx.x;
    int base = blockIdx.x * SCAN_CHUNK + t * SCAN_E;
    int loc[SCAN_E];
    int s = 0;
    #pragma unroll
    for (int i = 0; i < SCAN_E; ++i) {
        int idx = base + i;
        int v = (idx < n) ? cnt[idx] : 0;
        loc[i] = s; s += v;
    }
    lsum[t] = s; __syncthreads();
    for (int o = 1; o < SCAN_T; o <<= 1) {
        int v = (t >= o) ? lsum[t - o] : 0;
        __syncthreads();
        if (t >= o) lsum[t] += v;
        __syncthreads();
    }
    int texcl = lsum[t] - s;
    int cbase = psum[blockIdx.x];
    #pragma unroll
    for (int i = 0; i < SCAN_E; ++i) {
        int idx = base + i;
        if (idx < n) {
            int o = cbase + texcl + loc[i];
            off[idx] = o;
            cursor[idx] = o;
        }
    }
}

// pack {col | d<<30, ew_bits} -> single 8B scatter per edge
__global__ __launch_bounds__(256)
void csr_fill(const int* __restrict__ rows, const int* __restrict__ cols,
              const float* __restrict__ ew_in, int* __restrict__ cursor,
              int2* __restrict__ emeta, int E, int DE)
{
    int e = blockIdx.x * blockDim.x + threadIdx.x;
    if (e >= DE) return;
    int d = e / E;
    int pos = atomicAdd(&cursor[rows[e]], 1);
    uint32_t u = (uint32_t)cols[e] | ((uint32_t)d << 30);
    emeta[pos] = make_int2((int)u, __float_as_int(ew_in[e]));
}

// ---------------- fp32 tiled GEMM -> fp16 out: BM=128,BN=64,BK=16, 8x4 micro
template <bool LEAKY_IN>
__global__ __launch_bounds__(256)
void gemm_bias_h(const float* __restrict__ A,   // [M,K] fp32
                 const float* __restrict__ W,   // [K,N] fp32
                 const float* __restrict__ bias,// [N]
                 __half* __restrict__ out,      // [M,N] fp16
                 int M, int K, int N)
{
    const int BM = 128, BN = 64, BK = 16;
    __shared__ float As[BK][BM + 4];
    __shared__ float Ws[BK][BN];

    const int m0 = blockIdx.x * BM;
    const int n0 = blockIdx.y * BN;
    const int tid = threadIdx.x;
    const int tr = tid >> 4;   // 0..15 -> rows tr*8..tr*8+7
    const int tc = tid & 15;   // 0..15 -> cols tc*4..tc*4+3

    float acc[8][4] = {};

    const int nk = (K + BK - 1) / BK;
    for (int t = 0; t < nk; ++t) {
        const int k0 = t * BK;
        // A tile: 128x16 as 512 float4 loads, 2 per thread; store transposed
        #pragma unroll
        for (int i = 0; i < 2; ++i) {
            int f4 = tid + i * 256;      // 0..511
            int m  = f4 >> 2;            // 0..127
            int kq = (f4 & 3) * 4;       // 0,4,8,12
            int gm = m0 + m;
            float4 v = {0.f, 0.f, 0.f, 0.f};
            if (gm < M) {
                int gk = k0 + kq;
                if (gk + 3 < K) {
                    v = *reinterpret_cast<const float4*>(&A[(long)gm * K + gk]);
                } else {
                    float tmp[4] = {0.f, 0.f, 0.f, 0.f};
                    #pragma unroll
                    for (int q = 0; q < 4; ++q)
                        if (gk + q < K) tmp[q] = A[(long)gm * K + gk + q];
                    v.x = tmp[0]; v.y = tmp[1]; v.z = tmp[2]; v.w = tmp[3];
                }
                if (LEAKY_IN) {
                    v.x = v.x >= 0.f ? v.x : 0.2f * v.x;
                    v.y = v.y >= 0.f ? v.y : 0.2f * v.y;
                    v.z = v.z >= 0.f ? v.z : 0.2f * v.z;
                    v.w = v.w >= 0.f ? v.w : 0.2f * v.w;
                }
            }
            As[kq + 0][m] = v.x;
            As[kq + 1][m] = v.y;
            As[kq + 2][m] = v.z;
            As[kq + 3][m] = v.w;
        }
        // W tile: 16x64, one float4 per thread
        {
            int k = tid >> 4;
            int n = (tid & 15) * 4;
            int gk = k0 + k;
            float4 v = {0.f, 0.f, 0.f, 0.f};
            if (gk < K) v = *reinterpret_cast<const float4*>(&W[(long)gk * N + n0 + n]);
            *reinterpret_cast<float4*>(&Ws[k][n]) = v;
        }
        __syncthreads();

        #pragma unroll
        for (int kk = 0; kk < BK; ++kk) {
            float4 a0 = *reinterpret_cast<const float4*>(&As[kk][tr * 8]);
            float4 a1 = *reinterpret_cast<const float4*>(&As[kk][tr * 8 + 4]);
            float4 wv = *reinterpret_cast<const float4*>(&Ws[kk][tc * 4]);
            float a[8] = {a0.x, a0.y, a0.z, a0.w, a1.x, a1.y, a1.z, a1.w};
            float w[4] = {wv.x, wv.y, wv.z, wv.w};
            #pragma unroll
            for (int r = 0; r < 8; ++r)
                #pragma unroll
                for (int c = 0; c < 4; ++c)
                    acc[r][c] += a[r] * w[c];
        }
        __syncthreads();
    }

    #pragma unroll
    for (int r = 0; r < 8; ++r) {
        int gm = m0 + tr * 8 + r;
        if (gm < M) {
            int gn = n0 + tc * 4;
            float ox = acc[r][0] + bias[gn + 0];
            float oy = acc[r][1] + bias[gn + 1];
            float oz = acc[r][2] + bias[gn + 2];
            float ow = acc[r][3] + bias[gn + 3];
            __half2 h01 = __floats2half2_rn(ox, oy);
            __half2 h23 = __floats2half2_rn(oz, ow);
            uint2 pk;
            pk.x = *reinterpret_cast<uint32_t*>(&h01);
            pk.y = *reinterpret_cast<uint32_t*>(&h23);
            *reinterpret_cast<uint2*>(&out[(long)gm * N + gn]) = pk;
        }
    }
}

// ---------------- CSR aggregation: one wave per row, 4 gathers in flight ---
// supp fp16 [N,128]; each lane owns half2 (2 channels). Optional fused L2 norm.
template <bool NORM>
__global__ __launch_bounds__(256)
void aggregate_csr(const __half* __restrict__ supp,
                   const int* __restrict__ off,
                   const int* __restrict__ cnt,
                   const int2* __restrict__ emeta,
                   const float* __restrict__ sa,   // 3 softmax weights
                   float* __restrict__ out,        // [N,128] fp32
                   int N)
{
    int row = blockIdx.x * 4 + (threadIdx.x >> 6);
    int lane = threadIdx.x & 63;
    if (row >= N) return;

    const float s0 = sa[0], s1 = sa[1], s2 = sa[2];
    const uint32_t* sp = (const uint32_t*)supp;   // half2 per lane

    int j = off[row];
    const int end = j + cnt[row];
    float ax = 0.f, ay = 0.f;

    for (; j + 4 <= end; j += 4) {
        int2 m0 = emeta[j + 0];
        int2 m1 = emeta[j + 1];
        int2 m2 = emeta[j + 2];
        int2 m3 = emeta[j + 3];
        uint32_t u0 = (uint32_t)m0.x, u1 = (uint32_t)m1.x;
        uint32_t u2 = (uint32_t)m2.x, u3 = (uint32_t)m3.x;
        // 4 independent gathers issued back to back
        uint32_t p0 = sp[((long)(u0 & 0x3FFFFFFFu) << 6) + lane];
        uint32_t p1 = sp[((long)(u1 & 0x3FFFFFFFu) << 6) + lane];
        uint32_t p2 = sp[((long)(u2 & 0x3FFFFFFFu) << 6) + lane];
        uint32_t p3 = sp[((long)(u3 & 0x3FFFFFFFu) << 6) + lane];
        int d0 = u0 >> 30, d1 = u1 >> 30, d2 = u2 >> 30, d3 = u3 >> 30;
        float w0 = __int_as_float(m0.y) * (d0 == 0 ? s0 : (d0 == 1 ? s1 : s2));
        float w1 = __int_as_float(m1.y) * (d1 == 0 ? s0 : (d1 == 1 ? s1 : s2));
        float w2 = __int_as_float(m2.y) * (d2 == 0 ? s0 : (d2 == 1 ? s1 : s2));
        float w3 = __int_as_float(m3.y) * (d3 == 0 ? s0 : (d3 == 1 ? s1 : s2));
        float2 v0 = __half22float2(*reinterpret_cast<__half2*>(&p0));
        float2 v1 = __half22float2(*reinterpret_cast<__half2*>(&p1));
        float2 v2 = __half22float2(*reinterpret_cast<__half2*>(&p2));
        float2 v3 = __half22float2(*reinterpret_cast<__half2*>(&p3));
        ax += w0 * v0.x; ay += w0 * v0.y;
        ax += w1 * v1.x; ay += w1 * v1.y;
        ax += w2 * v2.x; ay += w2 * v2.y;
        ax += w3 * v3.x; ay += w3 * v3.y;
    }
    for (; j < end; ++j) {
        int2 m = emeta[j];
        uint32_t u = (uint32_t)m.x;
        uint32_t p = sp[((long)(u & 0x3FFFFFFFu) << 6) + lane];
        int d = u >> 30;
        float w = __int_as_float(m.y) * (d == 0 ? s0 : (d == 1 ? s1 : s2));
        float2 v = __half22float2(*reinterpret_cast<__half2*>(&p));
        ax += w * v.x; ay += w * v.y;
    }

    if (NORM) {
        float s = ax * ax + ay * ay;
        #pragma unroll
        for (int o = 32; o; o >>= 1) s += __shfl_xor(s, o);
        float inv = 1.f / fmaxf(sqrtf(s), 1e-12f);
        ax *= inv; ay *= inv;
    }
    *reinterpret_cast<float2*>(&out[(long)row * 128 + lane * 2]) = make_float2(ax, ay);
}

extern "C" void kernel_launch(void* const* d_in, const int* in_sizes, int n_in,
                              void* d_out, int out_size, void* d_ws, size_t ws_size,
                              hipStream_t stream)
{
    const float* x      = (const float*)d_in[0];
    const float* edge_w = (const float*)d_in[1];
    const float* w1     = (const float*)d_in[2];
    const float* b1     = (const float*)d_in[3];
    const float* a1     = (const float*)d_in[4];
    const float* w2     = (const float*)d_in[5];
    const float* b2     = (const float*)d_in[6];
    const float* a2     = (const float*)d_in[7];
    const int*   rows   = (const int*)d_in[8];
    const int*   cols   = (const int*)d_in[9];

    const int D    = in_sizes[4];            // 3
    const int HID  = in_sizes[3];            // 128
    const int OUTC = in_sizes[6];            // 128
    const int INC  = in_sizes[2] / HID;      // 300
    const int N    = in_sizes[0] / INC;      // 50000
    const int E    = in_sizes[1] / D;        // 600000
    const int DE   = D * E;

    float* out = (float*)d_out;

    // ---- workspace layout ----
    char* ws = (char*)d_ws;
    size_t p = 0;
    auto alloc = [&](size_t bytes) { void* q = ws + p; p = (p + bytes + 255) & ~(size_t)255; return q; };
    __half* supp  = (__half*)alloc((size_t)N * HID * sizeof(__half));   // 12.8 MB
    int*   counts = (int*)alloc((size_t)N * sizeof(int));
    int*   off    = (int*)alloc((size_t)N * sizeof(int));
    int*   cursor = (int*)alloc((size_t)N * sizeof(int));
    int*   psum   = (int*)alloc(1024 * sizeof(int));
    int2*  emeta  = (int2*)alloc((size_t)DE * sizeof(int2));            // 14.4 MB
    float* sa     = (float*)alloc(64 * sizeof(float));

    // ---- CSR build ----
    hipMemsetAsync(counts, 0, (size_t)N * sizeof(int), stream);
    prep_softmax<<<1, 64, 0, stream>>>(a1, a2, sa, D);

    int eblocks = (DE + 255) / 256;
    count_edges<<<eblocks, 256, 0, stream>>>(rows, counts, DE);

    int nchunks = (N + SCAN_CHUNK - 1) / SCAN_CHUNK;
    scan_partials<<<nchunks, SCAN_T, 0, stream>>>(counts, psum, N);
    scan_psum<<<1, 64, 0, stream>>>(psum, nchunks);
    scan_scatter<<<nchunks, SCAN_T, 0, stream>>>(counts, psum, off, cursor, N);

    csr_fill<<<eblocks, 256, 0, stream>>>(rows, cols, edge_w, cursor, emeta, E, DE);

    // ---- layer 1 ----
    dim3 g1((N + 127) / 128, HID / 64);
    gemm_bias_h<false><<<g1, 256, 0, stream>>>(x, w1, b1, supp, N, INC, HID);

    int rblocks = (N + 3) / 4;
    aggregate_csr<false><<<rblocks, 256, 0, stream>>>(supp, off, counts, emeta, sa, out, N);

    // ---- layer 2 (leaky applied while reading layer-1 output) ----
    dim3 g2((N + 127) / 128, OUTC / 64);
    gemm_bias_h<true><<<g2, 256, 0, stream>>>(out, w2, b2, supp, N, HID, OUTC);

    // fused L2-normalize in the final aggregation
    aggregate_csr<true><<<rblocks, 256, 0, stream>>>(supp, off, counts, emeta, sa + 8, out, N);
}

// Round 4
// 278.583 us; speedup vs baseline: 22.2041x; 1.7200x over previous
//
#include <hip/hip_runtime.h>
#include <hip/hip_fp16.h>

#define NB_MAX 512          // max buckets (N <= 65536, bucket = row>>7)
#define S1_CHUNK 8192       // edges per stage-1 block
#define S1_T 512            // stage-1 block size
#define S2_CAP 6144         // stage-2 LDS staging capacity (edges per bucket)

// ---------------- softmax of the two 3-element attention vectors ----------
__global__ void prep_softmax(const float* __restrict__ a1,
                             const float* __restrict__ a2,
                             float* __restrict__ sa, int D)
{
    if (blockIdx.x == 0 && threadIdx.x == 0) {
        float m1 = -1e30f, m2 = -1e30f;
        for (int i = 0; i < D; ++i) { m1 = fmaxf(m1, a1[i]); m2 = fmaxf(m2, a2[i]); }
        float s1 = 0.f, s2 = 0.f;
        for (int i = 0; i < D; ++i) { s1 += expf(a1[i] - m1); s2 += expf(a2[i] - m2); }
        for (int i = 0; i < D; ++i) {
            sa[i]     = expf(a1[i] - m1) / s1;
            sa[8 + i] = expf(a2[i] - m2) / s2;
        }
    }
}

// ---------------- stage 0: bucket histogram (bucket = row >> 7) -----------
__global__ __launch_bounds__(256)
void bucket_hist(const int* __restrict__ rows, int* __restrict__ gbh,
                 int DE, int NB)
{
    __shared__ int lh[NB_MAX];
    for (int i = threadIdx.x; i < NB_MAX; i += 256) lh[i] = 0;
    __syncthreads();
    int stride = gridDim.x * 256;
    for (int e = blockIdx.x * 256 + threadIdx.x; e < DE; e += stride)
        atomicAdd(&lh[rows[e] >> 7], 1);
    __syncthreads();
    for (int i = threadIdx.x; i < NB; i += 256)
        if (lh[i]) atomicAdd(&gbh[i], lh[i]);
}

// ---------------- bucket scan: boff (exclusive), gcursor init, off[N]=DE --
__global__ __launch_bounds__(NB_MAX)
void bucket_scan(const int* __restrict__ gbh, int* __restrict__ boff,
                 int* __restrict__ gcursor, int* __restrict__ off,
                 int NB, int N, int DE)
{
    __shared__ int sc[NB_MAX];
    int t = threadIdx.x;
    int own = (t < NB) ? gbh[t] : 0;
    sc[t] = own;
    __syncthreads();
    for (int o = 1; o < NB_MAX; o <<= 1) {
        int v = (t >= o) ? sc[t - o] : 0;
        __syncthreads();
        sc[t] += v;
        __syncthreads();
    }
    int excl = sc[t] - own;
    boff[t] = excl;
    boff[t + 1] = sc[t];          // last valid t (NB-1) writes boff[NB]=total
    gcursor[t] = excl;
    if (t == 0) { off[N] = DE; }
}

// ---------------- stage 1: LDS radix partition into bucketed buffer -------
// packed edge: .x = (row<<16) | fp16(ew) ; .y = col | (d<<17)
__global__ __launch_bounds__(S1_T)
void stage1_partition(const int* __restrict__ rows, const int* __restrict__ cols,
                      const float* __restrict__ ew, int* __restrict__ gcursor,
                      int2* __restrict__ gbuf, int E, int DE, int NB)
{
    __shared__ int lh[NB_MAX];
    __shared__ int sc[NB_MAX];
    __shared__ int rstart[NB_MAX];
    __shared__ int breserve[NB_MAX];
    __shared__ int cursor[NB_MAX];
    __shared__ int2 sorted[S1_CHUNK];
    __shared__ int  dstarr[S1_CHUNK];

    const int t = threadIdx.x;
    const int base = blockIdx.x * S1_CHUNK;
    const int cntE = min(S1_CHUNK, DE - base);

    for (int i = t; i < NB_MAX; i += S1_T) lh[i] = 0;
    __syncthreads();

    // pass A: histogram
    for (int p = t; p < cntE; p += S1_T)
        atomicAdd(&lh[rows[base + p] >> 7], 1);
    __syncthreads();

    // scan (inclusive Hillis-Steele over 512)
    int own = lh[t];
    sc[t] = own;
    __syncthreads();
    for (int o = 1; o < NB_MAX; o <<= 1) {
        int v = (t >= o) ? sc[t - o] : 0;
        __syncthreads();
        sc[t] += v;
        __syncthreads();
    }
    rstart[t] = sc[t] - own;
    cursor[t] = sc[t] - own;
    breserve[t] = (t < NB && own > 0) ? atomicAdd(&gcursor[t], own) : 0;
    __syncthreads();

    // pass C: LDS scatter into bucket-sorted order + destination calc
    for (int p = t; p < cntE; p += S1_T) {
        int e = base + p;
        int r = rows[e];
        int b = r >> 7;
        int d = e / E;
        __half hw = __float2half_rn(ew[e]);
        unsigned short hb = *reinterpret_cast<unsigned short*>(&hw);
        int rank = atomicAdd(&cursor[b], 1);
        sorted[rank] = make_int2((r << 16) | (int)hb,
                                 cols[e] | (d << 17));
        dstarr[rank] = breserve[b] + (rank - rstart[b]);
    }
    __syncthreads();

    // pass D: contiguous-run writes (consecutive p within a run -> consecutive dst)
    for (int p = t; p < cntE; p += S1_T)
        gbuf[dstarr[p]] = sorted[p];
}

// ---------------- stage 2: per-bucket row binning -> final CSR ------------
// final emeta: .x = col | (d<<17), .y = fp32 weight bits
__global__ __launch_bounds__(256)
void stage2_bin(const int2* __restrict__ gbuf, const int* __restrict__ boff,
                int2* __restrict__ emeta, int* __restrict__ off,
                int N, int NB)
{
    __shared__ int hist[128];
    __shared__ int sc[256];
    __shared__ int rs[128];
    __shared__ int cursor[128];
    __shared__ int2 stg[S2_CAP];

    const int b = blockIdx.x;
    const int t = threadIdx.x;
    const int r0 = b << 7;
    const int nrows = min(128, N - r0);
    const int base = boff[b];
    const int cntB = boff[b + 1] - base;

    if (t < 128) hist[t] = 0;
    __syncthreads();

    // pass 1: per-row histogram
    for (int p = t; p < cntB; p += 256) {
        int rl = ((unsigned)gbuf[base + p].x >> 16) - r0;
        atomicAdd(&hist[rl], 1);
    }
    __syncthreads();

    // scan over 128 (padded to 256)
    int own = (t < 128) ? hist[t] : 0;
    sc[t] = own;
    __syncthreads();
    for (int o = 1; o < 256; o <<= 1) {
        int v = (t >= o) ? sc[t - o] : 0;
        __syncthreads();
        sc[t] += v;
        __syncthreads();
    }
    if (t < 128) {
        rs[t] = sc[t] - own;
        cursor[t] = sc[t] - own;
    }
    __syncthreads();

    if (cntB <= S2_CAP) {
        // pass 2: LDS scatter into row-sorted order (unpack to final format)
        for (int p = t; p < cntB; p += 256) {
            int2 v = gbuf[base + p];
            int rl = ((unsigned)v.x >> 16) - r0;
            unsigned short hb = (unsigned short)(v.x & 0xFFFF);
            __half h = *reinterpret_cast<__half*>(&hb);
            int rank = atomicAdd(&cursor[rl], 1);
            stg[rank] = make_int2(v.y, __float_as_int(__half2float(h)));
        }
        __syncthreads();
        // pass 3: coalesced stream-out
        for (int p = t; p < cntB; p += 256)
            emeta[base + p] = stg[p];
    } else {
        // fallback (statistically never hit): direct global scatter in small window
        for (int p = t; p < cntB; p += 256) {
            int2 v = gbuf[base + p];
            int rl = ((unsigned)v.x >> 16) - r0;
            unsigned short hb = (unsigned short)(v.x & 0xFFFF);
            __half h = *reinterpret_cast<__half*>(&hb);
            int rank = atomicAdd(&cursor[rl], 1);
            emeta[base + rank] = make_int2(v.y, __float_as_int(__half2float(h)));
        }
    }
    // row offsets
    if (t < nrows) off[r0 + t] = base + rs[t];
}

// ---------------- fp32 tiled GEMM -> fp16 out: BM=128,BN=64,BK=16, 8x4 micro
template <bool LEAKY_IN>
__global__ __launch_bounds__(256)
void gemm_bias_h(const float* __restrict__ A,   // [M,K] fp32
                 const float* __restrict__ W,   // [K,N] fp32
                 const float* __restrict__ bias,// [N]
                 __half* __restrict__ out,      // [M,N] fp16
                 int M, int K, int N)
{
    const int BM = 128, BN = 64, BK = 16;
    __shared__ float As[BK][BM + 4];
    __shared__ float Ws[BK][BN];

    const int m0 = blockIdx.x * BM;
    const int n0 = blockIdx.y * BN;
    const int tid = threadIdx.x;
    const int tr = tid >> 4;
    const int tc = tid & 15;

    float acc[8][4] = {};

    const int nk = (K + BK - 1) / BK;
    for (int t = 0; t < nk; ++t) {
        const int k0 = t * BK;
        #pragma unroll
        for (int i = 0; i < 2; ++i) {
            int f4 = tid + i * 256;
            int m  = f4 >> 2;
            int kq = (f4 & 3) * 4;
            int gm = m0 + m;
            float4 v = {0.f, 0.f, 0.f, 0.f};
            if (gm < M) {
                int gk = k0 + kq;
                if (gk + 3 < K) {
                    v = *reinterpret_cast<const float4*>(&A[(long)gm * K + gk]);
                } else {
                    float tmp[4] = {0.f, 0.f, 0.f, 0.f};
                    #pragma unroll
                    for (int q = 0; q < 4; ++q)
                        if (gk + q < K) tmp[q] = A[(long)gm * K + gk + q];
                    v.x = tmp[0]; v.y = tmp[1]; v.z = tmp[2]; v.w = tmp[3];
                }
                if (LEAKY_IN) {
                    v.x = v.x >= 0.f ? v.x : 0.2f * v.x;
                    v.y = v.y >= 0.f ? v.y : 0.2f * v.y;
                    v.z = v.z >= 0.f ? v.z : 0.2f * v.z;
                    v.w = v.w >= 0.f ? v.w : 0.2f * v.w;
                }
            }
            As[kq + 0][m] = v.x;
            As[kq + 1][m] = v.y;
            As[kq + 2][m] = v.z;
            As[kq + 3][m] = v.w;
        }
        {
            int k = tid >> 4;
            int n = (tid & 15) * 4;
            int gk = k0 + k;
            float4 v = {0.f, 0.f, 0.f, 0.f};
            if (gk < K) v = *reinterpret_cast<const float4*>(&W[(long)gk * N + n0 + n]);
            *reinterpret_cast<float4*>(&Ws[k][n]) = v;
        }
        __syncthreads();

        #pragma unroll
        for (int kk = 0; kk < BK; ++kk) {
            float4 a0 = *reinterpret_cast<const float4*>(&As[kk][tr * 8]);
            float4 a1 = *reinterpret_cast<const float4*>(&As[kk][tr * 8 + 4]);
            float4 wv = *reinterpret_cast<const float4*>(&Ws[kk][tc * 4]);
            float a[8] = {a0.x, a0.y, a0.z, a0.w, a1.x, a1.y, a1.z, a1.w};
            float w[4] = {wv.x, wv.y, wv.z, wv.w};
            #pragma unroll
            for (int r = 0; r < 8; ++r)
                #pragma unroll
                for (int c = 0; c < 4; ++c)
                    acc[r][c] += a[r] * w[c];
        }
        __syncthreads();
    }

    #pragma unroll
    for (int r = 0; r < 8; ++r) {
        int gm = m0 + tr * 8 + r;
        if (gm < M) {
            int gn = n0 + tc * 4;
            float ox = acc[r][0] + bias[gn + 0];
            float oy = acc[r][1] + bias[gn + 1];
            float oz = acc[r][2] + bias[gn + 2];
            float ow = acc[r][3] + bias[gn + 3];
            __half2 h01 = __floats2half2_rn(ox, oy);
            __half2 h23 = __floats2half2_rn(oz, ow);
            uint2 pk;
            pk.x = *reinterpret_cast<uint32_t*>(&h01);
            pk.y = *reinterpret_cast<uint32_t*>(&h23);
            *reinterpret_cast<uint2*>(&out[(long)gm * N + gn]) = pk;
        }
    }
}

// ---------------- CSR aggregation: one wave per row, 8 gathers in flight ---
template <bool NORM>
__global__ __launch_bounds__(256)
void aggregate_csr(const __half* __restrict__ supp,
                   const int* __restrict__ off,     // [N+1]
                   const int2* __restrict__ emeta,
                   const float* __restrict__ sa,    // 3 softmax weights
                   float* __restrict__ out,         // [N,128] fp32
                   int N)
{
    int row = blockIdx.x * 4 + (threadIdx.x >> 6);
    int lane = threadIdx.x & 63;
    if (row >= N) return;

    const float s0 = sa[0], s1 = sa[1], s2 = sa[2];
    const uint32_t* sp = (const uint32_t*)supp;   // half2 per lane

    int j = off[row];
    const int end = off[row + 1];
    float ax = 0.f, ay = 0.f;

    for (; j + 8 <= end; j += 8) {
        int2 m[8];
        uint32_t p[8];
        #pragma unroll
        for (int q = 0; q < 8; ++q) m[q] = emeta[j + q];
        #pragma unroll
        for (int q = 0; q < 8; ++q) {
            uint32_t u = (uint32_t)m[q].x;
            p[q] = sp[((long)(u & 0x1FFFFu) << 6) + lane];
        }
        #pragma unroll
        for (int q = 0; q < 8; ++q) {
            uint32_t u = (uint32_t)m[q].x;
            int d = (int)(u >> 17);
            float w = __int_as_float(m[q].y) * (d == 0 ? s0 : (d == 1 ? s1 : s2));
            float2 v = __half22float2(*reinterpret_cast<__half2*>(&p[q]));
            ax += w * v.x; ay += w * v.y;
        }
    }
    for (; j + 4 <= end; j += 4) {
        int2 m[4];
        uint32_t p[4];
        #pragma unroll
        for (int q = 0; q < 4; ++q) m[q] = emeta[j + q];
        #pragma unroll
        for (int q = 0; q < 4; ++q) {
            uint32_t u = (uint32_t)m[q].x;
            p[q] = sp[((long)(u & 0x1FFFFu) << 6) + lane];
        }
        #pragma unroll
        for (int q = 0; q < 4; ++q) {
            uint32_t u = (uint32_t)m[q].x;
            int d = (int)(u >> 17);
            float w = __int_as_float(m[q].y) * (d == 0 ? s0 : (d == 1 ? s1 : s2));
            float2 v = __half22float2(*reinterpret_cast<__half2*>(&p[q]));
            ax += w * v.x; ay += w * v.y;
        }
    }
    for (; j < end; ++j) {
        int2 m = emeta[j];
        uint32_t u = (uint32_t)m.x;
        uint32_t pv = sp[((long)(u & 0x1FFFFu) << 6) + lane];
        int d = (int)(u >> 17);
        float w = __int_as_float(m.y) * (d == 0 ? s0 : (d == 1 ? s1 : s2));
        float2 v = __half22float2(*reinterpret_cast<__half2*>(&pv));
        ax += w * v.x; ay += w * v.y;
    }

    if (NORM) {
        float s = ax * ax + ay * ay;
        #pragma unroll
        for (int o = 32; o; o >>= 1) s += __shfl_xor(s, o);
        float inv = 1.f / fmaxf(sqrtf(s), 1e-12f);
        ax *= inv; ay *= inv;
    }
    *reinterpret_cast<float2*>(&out[(long)row * 128 + lane * 2]) = make_float2(ax, ay);
}

extern "C" void kernel_launch(void* const* d_in, const int* in_sizes, int n_in,
                              void* d_out, int out_size, void* d_ws, size_t ws_size,
                              hipStream_t stream)
{
    const float* x      = (const float*)d_in[0];
    const float* edge_w = (const float*)d_in[1];
    const float* w1     = (const float*)d_in[2];
    const float* b1     = (const float*)d_in[3];
    const float* a1     = (const float*)d_in[4];
    const float* w2     = (const float*)d_in[5];
    const float* b2     = (const float*)d_in[6];
    const float* a2     = (const float*)d_in[7];
    const int*   rows   = (const int*)d_in[8];
    const int*   cols   = (const int*)d_in[9];

    const int D    = in_sizes[4];            // 3
    const int HID  = in_sizes[3];            // 128
    const int OUTC = in_sizes[6];            // 128
    const int INC  = in_sizes[2] / HID;      // 300
    const int N    = in_sizes[0] / INC;      // 50000
    const int E    = in_sizes[1] / D;        // 600000
    const int DE   = D * E;
    const int NB   = (N + 127) >> 7;         // 391 buckets (requires N <= 65536)

    float* out = (float*)d_out;

    // ---- workspace layout ----
    char* ws = (char*)d_ws;
    size_t p = 0;
    auto alloc = [&](size_t bytes) { void* q = ws + p; p = (p + bytes + 255) & ~(size_t)255; return q; };
    __half* supp   = (__half*)alloc((size_t)N * HID * sizeof(__half));   // 12.8 MB
    int2*  gbuf    = (int2*)alloc((size_t)DE * sizeof(int2));            // 14.4 MB
    int2*  emeta   = (int2*)alloc((size_t)DE * sizeof(int2));            // 14.4 MB
    int*   off     = (int*)alloc((size_t)(N + 1) * sizeof(int));
    int*   gbh     = (int*)alloc((NB_MAX + 2) * sizeof(int));
    int*   boff    = (int*)alloc((NB_MAX + 2) * sizeof(int));
    int*   gcursor = (int*)alloc((NB_MAX + 2) * sizeof(int));
    float* sa      = (float*)alloc(64 * sizeof(float));

    // ---- CSR build (radix partition) ----
    hipMemsetAsync(gbh, 0, NB_MAX * sizeof(int), stream);
    prep_softmax<<<1, 64, 0, stream>>>(a1, a2, sa, D);

    bucket_hist<<<440, 256, 0, stream>>>(rows, gbh, DE, NB);
    bucket_scan<<<1, NB_MAX, 0, stream>>>(gbh, boff, gcursor, off, NB, N, DE);

    int s1blocks = (DE + S1_CHUNK - 1) / S1_CHUNK;
    stage1_partition<<<s1blocks, S1_T, 0, stream>>>(rows, cols, edge_w, gcursor,
                                                    gbuf, E, DE, NB);
    stage2_bin<<<NB, 256, 0, stream>>>(gbuf, boff, emeta, off, N, NB);

    // ---- layer 1 ----
    dim3 g1((N + 127) / 128, HID / 64);
    gemm_bias_h<false><<<g1, 256, 0, stream>>>(x, w1, b1, supp, N, INC, HID);

    int rblocks = (N + 3) / 4;
    aggregate_csr<false><<<rblocks, 256, 0, stream>>>(supp, off, emeta, sa, out, N);

    // ---- layer 2 (leaky applied while reading layer-1 output) ----
    dim3 g2((N + 127) / 128, OUTC / 64);
    gemm_bias_h<true><<<g2, 256, 0, stream>>>(out, w2, b2, supp, N, HID, OUTC);

    // fused L2-normalize in the final aggregation
    aggregate_csr<true><<<rblocks, 256, 0, stream>>>(supp, off, emeta, sa + 8, out, N);
}

// Round 5
// 220.733 us; speedup vs baseline: 28.0234x; 1.2621x over previous
//
#include <hip/hip_runtime.h>
#include <hip/hip_fp16.h>

#define NB_MAX 512          // max buckets (N <= 65536, bucket = row>>7)
#define S1_CHUNK 8192       // edges per stage-1 block
#define S1_T 512            // stage-1 block size
#define S2_CAP 6144         // stage-2 LDS staging capacity (edges per bucket)

typedef _Float16 half8 __attribute__((ext_vector_type(8)));
typedef float f32x4 __attribute__((ext_vector_type(4)));

// ---------------- softmax of the two 3-element attention vectors ----------
__global__ void prep_softmax(const float* __restrict__ a1,
                             const float* __restrict__ a2,
                             float* __restrict__ sa, int D)
{
    if (blockIdx.x == 0 && threadIdx.x == 0) {
        float m1 = -1e30f, m2 = -1e30f;
        for (int i = 0; i < D; ++i) { m1 = fmaxf(m1, a1[i]); m2 = fmaxf(m2, a2[i]); }
        float s1 = 0.f, s2 = 0.f;
        for (int i = 0; i < D; ++i) { s1 += expf(a1[i] - m1); s2 += expf(a2[i] - m2); }
        for (int i = 0; i < D; ++i) {
            sa[i]     = expf(a1[i] - m1) / s1;
            sa[8 + i] = expf(a2[i] - m2) / s2;
        }
    }
}

// ---------------- stage 0: bucket histogram (bucket = row >> 7) -----------
__global__ __launch_bounds__(256)
void bucket_hist(const int* __restrict__ rows, int* __restrict__ gbh,
                 int DE, int NB)
{
    __shared__ int lh[NB_MAX];
    for (int i = threadIdx.x; i < NB_MAX; i += 256) lh[i] = 0;
    __syncthreads();
    int stride = gridDim.x * 256;
    for (int e = blockIdx.x * 256 + threadIdx.x; e < DE; e += stride)
        atomicAdd(&lh[rows[e] >> 7], 1);
    __syncthreads();
    for (int i = threadIdx.x; i < NB; i += 256)
        if (lh[i]) atomicAdd(&gbh[i], lh[i]);
}

// ---------------- bucket scan: boff (exclusive), gcursor init, off[N]=DE --
__global__ __launch_bounds__(NB_MAX)
void bucket_scan(const int* __restrict__ gbh, int* __restrict__ boff,
                 int* __restrict__ gcursor, int* __restrict__ off,
                 int NB, int N, int DE)
{
    __shared__ int sc[NB_MAX];
    int t = threadIdx.x;
    int own = (t < NB) ? gbh[t] : 0;
    sc[t] = own;
    __syncthreads();
    for (int o = 1; o < NB_MAX; o <<= 1) {
        int v = (t >= o) ? sc[t - o] : 0;
        __syncthreads();
        sc[t] += v;
        __syncthreads();
    }
    int excl = sc[t] - own;
    boff[t] = excl;
    boff[t + 1] = sc[t];
    gcursor[t] = excl;
    if (t == 0) { off[N] = DE; }
}

// ---------------- stage 1: LDS radix partition into bucketed buffer -------
// packed edge: .x = (row<<16) | fp16(ew) ; .y = col | (d<<17)
__global__ __launch_bounds__(S1_T)
void stage1_partition(const int* __restrict__ rows, const int* __restrict__ cols,
                      const float* __restrict__ ew, int* __restrict__ gcursor,
                      int2* __restrict__ gbuf, int E, int DE, int NB)
{
    __shared__ int lh[NB_MAX];
    __shared__ int sc[NB_MAX];
    __shared__ int rstart[NB_MAX];
    __shared__ int breserve[NB_MAX];
    __shared__ int cursor[NB_MAX];
    __shared__ int2 sorted[S1_CHUNK];
    __shared__ int  dstarr[S1_CHUNK];

    const int t = threadIdx.x;
    const int base = blockIdx.x * S1_CHUNK;
    const int cntE = min(S1_CHUNK, DE - base);

    for (int i = t; i < NB_MAX; i += S1_T) lh[i] = 0;
    __syncthreads();

    for (int p = t; p < cntE; p += S1_T)
        atomicAdd(&lh[rows[base + p] >> 7], 1);
    __syncthreads();

    int own = lh[t];
    sc[t] = own;
    __syncthreads();
    for (int o = 1; o < NB_MAX; o <<= 1) {
        int v = (t >= o) ? sc[t - o] : 0;
        __syncthreads();
        sc[t] += v;
        __syncthreads();
    }
    rstart[t] = sc[t] - own;
    cursor[t] = sc[t] - own;
    breserve[t] = (t < NB && own > 0) ? atomicAdd(&gcursor[t], own) : 0;
    __syncthreads();

    for (int p = t; p < cntE; p += S1_T) {
        int e = base + p;
        int r = rows[e];
        int b = r >> 7;
        int d = e / E;
        __half hw = __float2half_rn(ew[e]);
        unsigned short hb = *reinterpret_cast<unsigned short*>(&hw);
        int rank = atomicAdd(&cursor[b], 1);
        sorted[rank] = make_int2((r << 16) | (int)hb,
                                 cols[e] | (d << 17));
        dstarr[rank] = breserve[b] + (rank - rstart[b]);
    }
    __syncthreads();

    for (int p = t; p < cntE; p += S1_T)
        gbuf[dstarr[p]] = sorted[p];
}

// ---------------- stage 2: per-bucket row binning -> final CSR ------------
__global__ __launch_bounds__(256)
void stage2_bin(const int2* __restrict__ gbuf, const int* __restrict__ boff,
                int2* __restrict__ emeta, int* __restrict__ off,
                int N, int NB)
{
    __shared__ int hist[128];
    __shared__ int sc[256];
    __shared__ int rs[128];
    __shared__ int cursor[128];
    __shared__ int2 stg[S2_CAP];

    const int b = blockIdx.x;
    const int t = threadIdx.x;
    const int r0 = b << 7;
    const int nrows = min(128, N - r0);
    const int base = boff[b];
    const int cntB = boff[b + 1] - base;

    if (t < 128) hist[t] = 0;
    __syncthreads();

    for (int p = t; p < cntB; p += 256) {
        int rl = ((unsigned)gbuf[base + p].x >> 16) - r0;
        atomicAdd(&hist[rl], 1);
    }
    __syncthreads();

    int own = (t < 128) ? hist[t] : 0;
    sc[t] = own;
    __syncthreads();
    for (int o = 1; o < 256; o <<= 1) {
        int v = (t >= o) ? sc[t - o] : 0;
        __syncthreads();
        sc[t] += v;
        __syncthreads();
    }
    if (t < 128) {
        rs[t] = sc[t] - own;
        cursor[t] = sc[t] - own;
    }
    __syncthreads();

    if (cntB <= S2_CAP) {
        for (int p = t; p < cntB; p += 256) {
            int2 v = gbuf[base + p];
            int rl = ((unsigned)v.x >> 16) - r0;
            unsigned short hb = (unsigned short)(v.x & 0xFFFF);
            __half h = *reinterpret_cast<__half*>(&hb);
            int rank = atomicAdd(&cursor[rl], 1);
            stg[rank] = make_int2(v.y, __float_as_int(__half2float(h)));
        }
        __syncthreads();
        for (int p = t; p < cntB; p += 256)
            emeta[base + p] = stg[p];
    } else {
        for (int p = t; p < cntB; p += 256) {
            int2 v = gbuf[base + p];
            int rl = ((unsigned)v.x >> 16) - r0;
            unsigned short hb = (unsigned short)(v.x & 0xFFFF);
            __half h = *reinterpret_cast<__half*>(&hb);
            int rank = atomicAdd(&cursor[rl], 1);
            emeta[base + rank] = make_int2(v.y, __float_as_int(__half2float(h)));
        }
    }
    if (t < nrows) off[r0 + t] = base + rs[t];
}

// ---------------- W pre-pack: fp32 [K,128] -> fp16 frag layout [kb][n][8] --
__global__ __launch_bounds__(256)
void pack_w(const float* __restrict__ W, _Float16* __restrict__ Wt,
            int K, int KBS)
{
    int idx = blockIdx.x * 256 + threadIdx.x;   // (kb, n)
    if (idx >= KBS * 128) return;
    int kb = idx >> 7, n = idx & 127;
    half8 h = {};
    #pragma unroll
    for (int j = 0; j < 8; ++j) {
        int k = kb * 8 + j;
        h[j] = (k < K) ? (_Float16)W[(long)k * 128 + n] : (_Float16)0.f;
    }
    *reinterpret_cast<half8*>(&Wt[(long)idx * 8]) = h;
}

// ---------------- MFMA GEMM: out[M,128] = A[M,K] @ W + bias, fp16 out -----
// BM=64, BN=128, BK=32, 256 threads (4 waves), mfma_f32_16x16x32_f16.
// A/B frags both filled with the same (lane-group,elem)->k map, so any HW
// k-permutation cancels; C/D layout: col=lane&15, row=(lane>>4)*4+reg.
template <bool AHALF>
__global__ __launch_bounds__(256)
void gemm_mfma(const void* __restrict__ Araw,
               const _Float16* __restrict__ Wt,   // packed [KP/8][128][8]
               const float* __restrict__ bias,
               _Float16* __restrict__ out,        // [M,128]
               int M, int K, int KP)
{
    __shared__ _Float16 Asl[4][64][8];
    __shared__ _Float16 Bsl[4][128][8];

    const int tid = threadIdx.x;
    const int m0 = blockIdx.x * 64;
    const int w = tid >> 6, l = tid & 63;
    const int wr0 = (w & 1) * 32, wc0 = (w >> 1) * 64;
    const int lg = l >> 4, lm = l & 15;

    f32x4 acc[2][4] = {};

    const int nk = KP >> 5;
    for (int t = 0; t < nk; ++t) {
        const int k0 = t << 5;
        // ---- A stage: 64 rows x 32 k
        {
            int m = tid >> 2, kq = (tid & 3) * 8;
            int gm = m0 + m;
            half8 h = {};
            if (AHALF) {
                if (gm < M)
                    h = *reinterpret_cast<const half8*>(
                        (const _Float16*)Araw + (long)gm * K + k0 + kq);
            } else {
                const float* A = (const float*)Araw;
                if (gm < M) {
                    float v[8];
                    if (k0 + kq + 7 < K) {
                        float4 f0 = *reinterpret_cast<const float4*>(A + (long)gm * K + k0 + kq);
                        float4 f1 = *reinterpret_cast<const float4*>(A + (long)gm * K + k0 + kq + 4);
                        v[0]=f0.x; v[1]=f0.y; v[2]=f0.z; v[3]=f0.w;
                        v[4]=f1.x; v[5]=f1.y; v[6]=f1.z; v[7]=f1.w;
                    } else {
                        #pragma unroll
                        for (int j = 0; j < 8; ++j) {
                            int k = k0 + kq + j;
                            v[j] = (k < K) ? A[(long)gm * K + k] : 0.f;
                        }
                    }
                    #pragma unroll
                    for (int j = 0; j < 8; ++j) h[j] = (_Float16)v[j];
                }
            }
            *reinterpret_cast<half8*>(&Asl[kq >> 3][m][0]) = h;
        }
        // ---- B stage: straight copy of packed region (4 kb x 128 n x 8)
        {
            const half8* src = reinterpret_cast<const half8*>(Wt + (long)t * 4096);
            half8* dst = reinterpret_cast<half8*>(Bsl);
            dst[tid] = src[tid];
            dst[tid + 256] = src[tid + 256];
        }
        __syncthreads();

        half8 af[2], bf[4];
        #pragma unroll
        for (int rt = 0; rt < 2; ++rt)
            af[rt] = *reinterpret_cast<const half8*>(&Asl[lg][wr0 + rt * 16 + lm][0]);
        #pragma unroll
        for (int ct = 0; ct < 4; ++ct)
            bf[ct] = *reinterpret_cast<const half8*>(&Bsl[lg][wc0 + ct * 16 + lm][0]);
        #pragma unroll
        for (int rt = 0; rt < 2; ++rt)
            #pragma unroll
            for (int ct = 0; ct < 4; ++ct)
                acc[rt][ct] = __builtin_amdgcn_mfma_f32_16x16x32_f16(
                    af[rt], bf[ct], acc[rt][ct], 0, 0, 0);
        __syncthreads();
    }

    // ---- epilogue: C/D col=lm, row=lg*4+q
    #pragma unroll
    for (int rt = 0; rt < 2; ++rt) {
        #pragma unroll
        for (int ct = 0; ct < 4; ++ct) {
            int col = wc0 + ct * 16 + lm;
            float b = bias[col];
            #pragma unroll
            for (int q = 0; q < 4; ++q) {
                int row = m0 + wr0 + rt * 16 + lg * 4 + q;
                if (row < M)
                    out[(long)row * 128 + col] = (_Float16)(acc[rt][ct][q] + b);
            }
        }
    }
}

// ---------------- CSR aggregation: one wave per row, 8 gathers in flight ---
// LEAKY_H: apply LeakyReLU(0.2) and write fp16 (layer-1). NORM: L2-normalize
// and write fp32 (final layer).
template <bool NORM, bool LEAKY_H>
__global__ __launch_bounds__(256)
void aggregate_csr(const _Float16* __restrict__ supp,
                   const int* __restrict__ off,     // [N+1]
                   const int2* __restrict__ emeta,
                   const float* __restrict__ sa,    // 3 softmax weights
                   float* __restrict__ outf,        // [N,128] fp32 (NORM path)
                   uint32_t* __restrict__ outh,     // [N,64] half2 (LEAKY_H path)
                   int N)
{
    int row = blockIdx.x * 4 + (threadIdx.x >> 6);
    int lane = threadIdx.x & 63;
    if (row >= N) return;

    const float s0 = sa[0], s1 = sa[1], s2 = sa[2];
    const uint32_t* sp = (const uint32_t*)supp;   // half2 per lane

    int j = off[row];
    const int end = off[row + 1];
    float ax = 0.f, ay = 0.f;

    for (; j + 8 <= end; j += 8) {
        int2 m[8];
        uint32_t p[8];
        #pragma unroll
        for (int q = 0; q < 8; ++q) m[q] = emeta[j + q];
        #pragma unroll
        for (int q = 0; q < 8; ++q) {
            uint32_t u = (uint32_t)m[q].x;
            p[q] = sp[((long)(u & 0x1FFFFu) << 6) + lane];
        }
        #pragma unroll
        for (int q = 0; q < 8; ++q) {
            uint32_t u = (uint32_t)m[q].x;
            int d = (int)(u >> 17);
            float w = __int_as_float(m[q].y) * (d == 0 ? s0 : (d == 1 ? s1 : s2));
            float2 v = __half22float2(*reinterpret_cast<__half2*>(&p[q]));
            ax += w * v.x; ay += w * v.y;
        }
    }
    for (; j + 4 <= end; j += 4) {
        int2 m[4];
        uint32_t p[4];
        #pragma unroll
        for (int q = 0; q < 4; ++q) m[q] = emeta[j + q];
        #pragma unroll
        for (int q = 0; q < 4; ++q) {
            uint32_t u = (uint32_t)m[q].x;
            p[q] = sp[((long)(u & 0x1FFFFu) << 6) + lane];
        }
        #pragma unroll
        for (int q = 0; q < 4; ++q) {
            uint32_t u = (uint32_t)m[q].x;
            int d = (int)(u >> 17);
            float w = __int_as_float(m[q].y) * (d == 0 ? s0 : (d == 1 ? s1 : s2));
            float2 v = __half22float2(*reinterpret_cast<__half2*>(&p[q]));
            ax += w * v.x; ay += w * v.y;
        }
    }
    for (; j < end; ++j) {
        int2 m = emeta[j];
        uint32_t u = (uint32_t)m.x;
        uint32_t pv = sp[((long)(u & 0x1FFFFu) << 6) + lane];
        int d = (int)(u >> 17);
        float w = __int_as_float(m.y) * (d == 0 ? s0 : (d == 1 ? s1 : s2));
        float2 v = __half22float2(*reinterpret_cast<__half2*>(&pv));
        ax += w * v.x; ay += w * v.y;
    }

    if (LEAKY_H) {
        ax = ax >= 0.f ? ax : 0.2f * ax;
        ay = ay >= 0.f ? ay : 0.2f * ay;
        __half2 h = __floats2half2_rn(ax, ay);
        outh[(long)row * 64 + lane] = *reinterpret_cast<uint32_t*>(&h);
    } else {
        if (NORM) {
            float s = ax * ax + ay * ay;
            #pragma unroll
            for (int o = 32; o; o >>= 1) s += __shfl_xor(s, o);
            float inv = 1.f / fmaxf(sqrtf(s), 1e-12f);
            ax *= inv; ay *= inv;
        }
        *reinterpret_cast<float2*>(&outf[(long)row * 128 + lane * 2]) = make_float2(ax, ay);
    }
}

extern "C" void kernel_launch(void* const* d_in, const int* in_sizes, int n_in,
                              void* d_out, int out_size, void* d_ws, size_t ws_size,
                              hipStream_t stream)
{
    const float* x      = (const float*)d_in[0];
    const float* edge_w = (const float*)d_in[1];
    const float* w1     = (const float*)d_in[2];
    const float* b1     = (const float*)d_in[3];
    const float* a1     = (const float*)d_in[4];
    const float* w2     = (const float*)d_in[5];
    const float* b2     = (const float*)d_in[6];
    const float* a2     = (const float*)d_in[7];
    const int*   rows   = (const int*)d_in[8];
    const int*   cols   = (const int*)d_in[9];

    const int D    = in_sizes[4];            // 3
    const int HID  = in_sizes[3];            // 128
    const int INC  = in_sizes[2] / HID;      // 300
    const int N    = in_sizes[0] / INC;      // 50000
    const int E    = in_sizes[1] / D;        // 600000
    const int DE   = D * E;
    const int NB   = (N + 127) >> 7;         // 391 buckets

    const int KP1  = (INC + 31) & ~31;       // 320
    const int KBS1 = KP1 / 8;                // 40
    const int KBS2 = HID / 8;                // 16

    float* out = (float*)d_out;

    // ---- workspace layout ----
    char* ws = (char*)d_ws;
    size_t p = 0;
    auto alloc = [&](size_t bytes) { void* q = ws + p; p = (p + bytes + 255) & ~(size_t)255; return q; };
    _Float16* supp  = (_Float16*)alloc((size_t)N * 128 * sizeof(_Float16));  // 12.8 MB
    _Float16* hsupp = (_Float16*)alloc((size_t)N * 128 * sizeof(_Float16));  // 12.8 MB
    int2*  gbuf    = (int2*)alloc((size_t)DE * sizeof(int2));                // 14.4 MB
    int2*  emeta   = (int2*)alloc((size_t)DE * sizeof(int2));                // 14.4 MB
    int*   off     = (int*)alloc((size_t)(N + 1) * sizeof(int));
    int*   gbh     = (int*)alloc((NB_MAX + 2) * sizeof(int));
    int*   boff    = (int*)alloc((NB_MAX + 2) * sizeof(int));
    int*   gcursor = (int*)alloc((NB_MAX + 2) * sizeof(int));
    _Float16* wt1  = (_Float16*)alloc((size_t)KBS1 * 128 * 8 * sizeof(_Float16));
    _Float16* wt2  = (_Float16*)alloc((size_t)KBS2 * 128 * 8 * sizeof(_Float16));
    float* sa      = (float*)alloc(64 * sizeof(float));

    // ---- CSR build (radix partition) ----
    hipMemsetAsync(gbh, 0, NB_MAX * sizeof(int), stream);
    prep_softmax<<<1, 64, 0, stream>>>(a1, a2, sa, D);

    bucket_hist<<<440, 256, 0, stream>>>(rows, gbh, DE, NB);
    bucket_scan<<<1, NB_MAX, 0, stream>>>(gbh, boff, gcursor, off, NB, N, DE);

    int s1blocks = (DE + S1_CHUNK - 1) / S1_CHUNK;
    stage1_partition<<<s1blocks, S1_T, 0, stream>>>(rows, cols, edge_w, gcursor,
                                                    gbuf, E, DE, NB);
    stage2_bin<<<NB, 256, 0, stream>>>(gbuf, boff, emeta, off, N, NB);

    // ---- weight pre-pack ----
    pack_w<<<(KBS1 * 128 + 255) / 256, 256, 0, stream>>>(w1, wt1, INC, KBS1);
    pack_w<<<(KBS2 * 128 + 255) / 256, 256, 0, stream>>>(w2, wt2, HID, KBS2);

    // ---- layer 1: supp = fp16(x @ w1 + b1) ----
    int gblocks = (N + 63) / 64;
    gemm_mfma<false><<<gblocks, 256, 0, stream>>>(x, wt1, b1, supp, N, INC, KP1);

    // ---- layer 1 aggregation (+leaky, fp16 out) ----
    int rblocks = (N + 3) / 4;
    aggregate_csr<false, true><<<rblocks, 256, 0, stream>>>(
        supp, off, emeta, sa, nullptr, (uint32_t*)hsupp, N);

    // ---- layer 2: supp = fp16(hsupp @ w2 + b2) ----
    gemm_mfma<true><<<gblocks, 256, 0, stream>>>(hsupp, wt2, b2, supp, N, HID, HID);

    // ---- layer 2 aggregation + fused L2 normalize -> d_out ----
    aggregate_csr<true, false><<<rblocks, 256, 0, stream>>>(
        supp, off, emeta, sa + 8, out, nullptr, N);
}